// Round 4
// baseline (252.539 us; speedup 1.0000x reference)
//
#include <hip/hip_runtime.h>
#include <hip/hip_bf16.h>
#include <stdint.h>

typedef __bf16 bf16x8 __attribute__((ext_vector_type(8)));
typedef float f32x4 __attribute__((ext_vector_type(4)));

#define RATIO   128
#define HEADDIM 512
#define RD      64
#define NCW     64
#define BATCH   2
#define SEQ     8192
#define DIM     4096

__device__ __forceinline__ void gload16(const void* g, void* l) {
  __builtin_amdgcn_global_load_lds(
      (__attribute__((address_space(1))) const void*)g,
      (__attribute__((address_space(3))) void*)l, 16, 0, 0);
}

__device__ __forceinline__ __bf16 cvt_bf16(float f) {
  __hip_bfloat16 h = __float2bfloat16(f);
  return *reinterpret_cast<__bf16*>(&h);
}

// ---------------- prep: build W' swizzled bf16 tiles ----------------
// W' col-in-block C (0..255): channel = j*128 + (C>>4)*8 + (C&7), tensor = (C>>3)&1
// (16-col fragment = 8 kv channels + the same 8 sc channels).
// Tile layout: [j 4][k0t 64][row 256][slot 8] chunks of 8 bf16 along k,
// chunk(row,slot) holds k = k0t*64 + (slot^(row&7))*8 .. +8  (XOR pre-swizzle).
__global__ __launch_bounds__(256) void prep_weights(
    const float* __restrict__ w0, const float* __restrict__ w1,
    __hip_bfloat16* __restrict__ wTs) {
  __shared__ float tile[2][64][128];
  const int k0t = blockIdx.x;   // 0..63
  const int j   = blockIdx.y;   // 0..3
  const int t   = threadIdx.x;
  const int kk  = t >> 5;       // 0..7
  const int c4  = (t & 31) * 4;
  #pragma unroll
  for (int tensor = 0; tensor < 2; ++tensor) {
    const float* in = tensor ? w1 : w0;
    #pragma unroll
    for (int p = 0; p < 8; ++p) {
      const int k = p * 8 + kk;
      const f32x4 v = *reinterpret_cast<const f32x4*>(
          in + (size_t)(k0t * 64 + k) * HEADDIM + j * 128 + c4);
      tile[tensor][k][c4 + 0] = v[0]; tile[tensor][k][c4 + 1] = v[1];
      tile[tensor][k][c4 + 2] = v[2]; tile[tensor][k][c4 + 3] = v[3];
    }
  }
  __syncthreads();
  const int row    = t;                          // 0..255
  const int chloc  = (row >> 4) * 8 + (row & 7); // 0..127
  const int tensor = (row >> 3) & 1;
  __hip_bfloat16* ob = wTs + (((size_t)j * 64 + k0t) * 2048 + (size_t)row * 8) * 8;
  #pragma unroll
  for (int slot = 0; slot < 8; ++slot) {
    const int k8 = (slot ^ (row & 7)) * 8;
    bf16x8 c;
    #pragma unroll
    for (int jj = 0; jj < 8; ++jj) c[jj] = cvt_bf16(tile[tensor][k8 + jj][chloc]);
    *reinterpret_cast<bf16x8*>(ob + slot * 8) = c;
  }
}

// ---------------- fused 256x256 GEMM + softmax-pool ----------------
__global__ __launch_bounds__(512, 2) void gemm_pool_kernel(
    const float* __restrict__ x,
    const __hip_bfloat16* __restrict__ wTs,
    const float* __restrict__ ape,       // [128][512] f32
    float* __restrict__ comp) {          // [2][64][512] f32
  __shared__ char smem[131072];          // 2 x (A 32KB + B 32KB)

  const int u      = blockIdx.x;         // 256 blocks
  const int rowblk = u & 63;             // 4 col-blocks of a rowblk share an XCD
  const int colblk = u >> 6;
  const int tid  = threadIdx.x;
  const int lane = tid & 63;
  const int wid  = tid >> 6;             // 8 waves: 2(M) x 4(N)
  const int wm   = wid >> 2, wn = wid & 3;

  const float* xw = x + (size_t)rowblk * 256 * DIM;
  const __hip_bfloat16* wsrc = wTs + (size_t)colblk * 64 * 2048 * 8;

  // A staging: thread -> (row, half-of-64k)
  const int arow  = tid >> 1;
  const int ahalf = tid & 1;
  const float* aBase = xw + (size_t)arow * DIM + ahalf * 32;

  f32x4 acc[8][4];
  #pragma unroll
  for (int i = 0; i < 8; ++i)
    #pragma unroll
    for (int j = 0; j < 4; ++j) acc[i][j] = {0.f, 0.f, 0.f, 0.f};

  auto issueA = [&](int k0t, f32x4* pv) {
    const f32x4* s = reinterpret_cast<const f32x4*>(aBase + k0t * 64);
    #pragma unroll
    for (int q = 0; q < 8; ++q) pv[q] = s[q];
  };
  auto issueB = [&](int k0t, char* bufB) {
    #pragma unroll
    for (int i = 0; i < 4; ++i) {
      const int ch = wid * 256 + i * 64;       // wave-uniform chunk base
      gload16(wsrc + ((size_t)k0t * 2048 + ch + lane) * 8, bufB + ch * 16);
    }
  };
  auto writeA = [&](char* bufA, const f32x4* pv) {
    char* ab = bufA + arow * 128;
    #pragma unroll
    for (int q = 0; q < 4; ++q) {
      bf16x8 c;
      #pragma unroll
      for (int jj = 0; jj < 4; ++jj) {
        c[jj]     = cvt_bf16(pv[2 * q][jj]);
        c[4 + jj] = cvt_bf16(pv[2 * q + 1][jj]);
      }
      *reinterpret_cast<bf16x8*>(ab + (((ahalf * 4 + q) ^ (arow & 7)) << 4)) = c;
    }
  };
  auto compute = [&](const char* bufA, const char* bufB) {
    #pragma unroll
    for (int s = 0; s < 2; ++s) {
      const int c16 = s * 4 + (lane >> 4);
      bf16x8 af[8];
      #pragma unroll
      for (int mt = 0; mt < 8; ++mt) {
        const int r = wm * 128 + mt * 16 + (lane & 15);
        af[mt] = *reinterpret_cast<const bf16x8*>(bufA + r * 128 + ((c16 ^ (r & 7)) << 4));
      }
      #pragma unroll
      for (int nt = 0; nt < 4; ++nt) {
        const int cc = wn * 64 + nt * 16 + (lane & 15);
        const bf16x8 bf = *reinterpret_cast<const bf16x8*>(bufB + cc * 128 + ((c16 ^ (cc & 7)) << 4));
        #pragma unroll
        for (int mt = 0; mt < 8; ++mt)
          acc[mt][nt] = __builtin_amdgcn_mfma_f32_16x16x32_bf16(af[mt], bf, acc[mt][nt], 0, 0, 0);
      }
    }
  };

  // prologue: stage K-tile 0 into buffer 0
  {
    f32x4 pv[8];
    issueA(0, pv);
    issueB(0, smem + 32768);
    asm volatile("s_waitcnt vmcnt(0)" ::: "memory");
    writeA(smem, pv);
  }
  __syncthreads();

  int cur = 0;
  for (int t = 0; t < 64; ++t) {
    char* A  = smem + cur * 65536;
    char* B  = A + 32768;
    char* An = smem + (cur ^ 1) * 65536;
    char* Bn = An + 32768;
    f32x4 nv[8];
    if (t < 63) {                       // issue next tile's loads BEFORE MFMA
      issueA(t + 1, nv);
      issueB(t + 1, Bn);
    }
    compute(A, B);                      // ~2500 cyc of MFMA hides the load latency
    if (t < 63) {
      asm volatile("s_waitcnt vmcnt(0)" ::: "memory");
      writeA(An, nv);
    }
    __syncthreads();                    // publish next buffer; all reads of cur done
    cur ^= 1;
  }

  // ---- epilogue: in-register softmax-pool; kv<->sc pairing via shfl_xor(8) ----
  const int win = rowblk * 2 + wm;       // global window id (= b*64 + nc)
  #pragma unroll
  for (int nt = 0; nt < 4; ++nt) {
    const int f  = wn * 4 + nt;
    const int ch = colblk * 128 + f * 8 + (lane & 7);
    if (lane & 8) {                      // hi lanes hold sc: add ape first
      #pragma unroll
      for (int mt = 0; mt < 8; ++mt)
        #pragma unroll
        for (int r = 0; r < 4; ++r) {
          const int rw = mt * 16 + ((lane >> 4) & 3) * 4 + r;
          acc[mt][nt][r] += ape[(size_t)rw * HEADDIM + ch];
        }
    }
    float m = -3.0e38f;
    #pragma unroll
    for (int mt = 0; mt < 8; ++mt)
      #pragma unroll
      for (int r = 0; r < 4; ++r) m = fmaxf(m, acc[mt][nt][r]);
    m = fmaxf(m, __shfl_xor(m, 16));
    m = fmaxf(m, __shfl_xor(m, 32));
    float den = 0.f, num = 0.f;
    #pragma unroll
    for (int mt = 0; mt < 8; ++mt)
      #pragma unroll
      for (int r = 0; r < 4; ++r) {
        const float other = __shfl_xor(acc[mt][nt][r], 8);  // hi lane gets kv
        const float e = __expf(acc[mt][nt][r] - m);
        den += e;
        num += e * other;
      }
    den += __shfl_xor(den, 16); den += __shfl_xor(den, 32);
    num += __shfl_xor(num, 16); num += __shfl_xor(num, 32);
    if ((lane & 8) && (lane < 16))
      comp[(size_t)win * HEADDIM + ch] = num / den;
  }
}

// ---------------- RMSNorm + RoPE + scatter (all f32) ----------------
__global__ __launch_bounds__(64) void finalize_kernel(
    const float* __restrict__ comp,
    const float* __restrict__ nw,
    const float* __restrict__ cosg,
    const float* __restrict__ sing,
    const int* __restrict__ bo,
    float* __restrict__ out) {
  const int win = blockIdx.x;          // 0..127
  const int b = win >> 6, nc = win & 63;
  const int t = threadIdx.x;
  const float* cw = comp + (size_t)win * HEADDIM;

  float v[8];
  float ss = 0.f;
  #pragma unroll
  for (int j = 0; j < 8; ++j) { v[j] = cw[t * 8 + j]; ss += v[j] * v[j]; }
  #pragma unroll
  for (int o = 32; o; o >>= 1) ss += __shfl_xor(ss, o);
  const float scale = rsqrtf(ss / 512.0f + 1e-6f);

  float w[8];
  #pragma unroll
  for (int j = 0; j < 8; ++j) w[j] = v[j] * scale * nw[t * 8 + j];

  const int phys = bo[b];
  float* op = out + ((size_t)phys * NCW + nc) * HEADDIM + t * 8;
  if (t * 8 < HEADDIM - RD) {
    #pragma unroll
    for (int j = 0; j < 8; ++j) op[j] = w[j];
  } else {
    const int pos = nc * RATIO;
    #pragma unroll
    for (int j = 0; j < 8; j += 2) {
      const int i = (t * 8 + j - (HEADDIM - RD)) >> 1;
      const float co = cosg[(size_t)pos * 32 + i];
      const float si = sing[(size_t)pos * 32 + i];
      op[j]     = w[j] * co - w[j + 1] * si;
      op[j + 1] = w[j] * si + w[j + 1] * co;
    }
  }
}

extern "C" void kernel_launch(void* const* d_in, const int* in_sizes, int n_in,
                              void* d_out, int out_size, void* d_ws, size_t ws_size,
                              hipStream_t stream) {
  const float* x     = (const float*)d_in[0];
  const float* wkv   = (const float*)d_in[1];
  const float* wgate = (const float*)d_in[2];
  const float* ape   = (const float*)d_in[3];
  const float* nw    = (const float*)d_in[4];
  const float* cosg  = (const float*)d_in[5];
  const float* sing  = (const float*)d_in[6];
  const int*   bo    = (const int*)d_in[7];
  float* out = (float*)d_out;

  __hip_bfloat16* wTs = (__hip_bfloat16*)d_ws;                        // 8 MB swizzled W'
  float* comp = (float*)((char*)d_ws + (size_t)8 * 1024 * 1024);      // 256 KB

  (void)hipMemsetAsync(d_out, 0, (size_t)out_size * sizeof(float), stream);
  prep_weights<<<dim3(64, 4), 256, 0, stream>>>(wkv, wgate, wTs);
  gemm_pool_kernel<<<dim3(256), 512, 0, stream>>>(x, wTs, ape, comp);
  finalize_kernel<<<dim3(128), 64, 0, stream>>>(comp, nw, cosg, sing, bo, out);
}

// Round 5
// 243.007 us; speedup vs baseline: 1.0392x; 1.0392x over previous
//
#include <hip/hip_runtime.h>
#include <hip/hip_bf16.h>
#include <stdint.h>

typedef __bf16 bf16x8 __attribute__((ext_vector_type(8)));
typedef float f32x4 __attribute__((ext_vector_type(4)));

#define RATIO   128
#define HEADDIM 512
#define RD      64
#define NCW     64
#define BATCH   2
#define SEQ     8192
#define DIM     4096

__device__ __forceinline__ void gload16(const void* g, void* l) {
  __builtin_amdgcn_global_load_lds(
      (__attribute__((address_space(1))) const void*)g,
      (__attribute__((address_space(3))) void*)l, 16, 0, 0);
}

__device__ __forceinline__ __bf16 cvt_bf16(float f) {
  __hip_bfloat16 h = __float2bfloat16(f);
  return *reinterpret_cast<__bf16*>(&h);
}

// ---------------- prep: build W' swizzled bf16 tiles ----------------
// W' col-in-block C (0..255): channel = j*128 + (C>>4)*8 + (C&7), tensor = (C>>3)&1
// (16-col fragment = 8 kv channels + the same 8 sc channels).
// Tile layout: [j 4][k0t 64][row 256][slot 8] chunks of 8 bf16 along k,
// chunk(row,slot) holds k = k0t*64 + (slot^(row&7))*8 .. +8  (XOR pre-swizzle).
__global__ __launch_bounds__(256) void prep_weights(
    const float* __restrict__ w0, const float* __restrict__ w1,
    __hip_bfloat16* __restrict__ wTs) {
  __shared__ float tile[2][64][128];
  const int k0t = blockIdx.x;   // 0..63
  const int j   = blockIdx.y;   // 0..3
  const int t   = threadIdx.x;
  const int kk  = t >> 5;       // 0..7
  const int c4  = (t & 31) * 4;
  #pragma unroll
  for (int tensor = 0; tensor < 2; ++tensor) {
    const float* in = tensor ? w1 : w0;
    #pragma unroll
    for (int p = 0; p < 8; ++p) {
      const int k = p * 8 + kk;
      const f32x4 v = *reinterpret_cast<const f32x4*>(
          in + (size_t)(k0t * 64 + k) * HEADDIM + j * 128 + c4);
      tile[tensor][k][c4 + 0] = v[0]; tile[tensor][k][c4 + 1] = v[1];
      tile[tensor][k][c4 + 2] = v[2]; tile[tensor][k][c4 + 3] = v[3];
    }
  }
  __syncthreads();
  const int row    = t;                          // 0..255
  const int chloc  = (row >> 4) * 8 + (row & 7); // 0..127
  const int tensor = (row >> 3) & 1;
  __hip_bfloat16* ob = wTs + (((size_t)j * 64 + k0t) * 2048 + (size_t)row * 8) * 8;
  #pragma unroll
  for (int slot = 0; slot < 8; ++slot) {
    const int k8 = (slot ^ (row & 7)) * 8;
    bf16x8 c;
    #pragma unroll
    for (int jj = 0; jj < 8; ++jj) c[jj] = cvt_bf16(tile[tensor][k8 + jj][chloc]);
    *reinterpret_cast<bf16x8*>(ob + slot * 8) = c;
  }
}

// ---------------- fused 256x256 GEMM + softmax-pool, counted-vmcnt pipeline ----------------
__global__ __launch_bounds__(512, 2) void gemm_pool_kernel(
    const float* __restrict__ x,
    const __hip_bfloat16* __restrict__ wTs,
    const float* __restrict__ ape,       // [128][512] f32
    float* __restrict__ comp) {          // [2][64][512] f32
  __shared__ char smem[131072];          // 2 x (A 32KB + B 32KB)

  const int u      = blockIdx.x;                 // 256 blocks
  const int rowblk = ((u >> 3) & 7) * 8 + (u & 7); // u%8 == rowblk%8 -> 4 colblks/XCD share x panel
  const int colblk = u >> 6;
  const int tid  = threadIdx.x;
  const int lane = tid & 63;
  const int wid  = tid >> 6;             // 8 waves: 2(M) x 4(N)
  const int wm   = wid >> 2, wn = wid & 3;

  const float* xw = x + (size_t)rowblk * 256 * DIM;
  const __hip_bfloat16* wsrc = wTs + (size_t)colblk * 64 * 2048 * 8;

  // A staging: 2 threads per row, each covers 32 f32 (8 f32x4) per K-tile
  const int arow  = tid >> 1;
  const int ahalf = tid & 1;
  const float* aBase = xw + (size_t)arow * DIM + ahalf * 32;

  f32x4 acc[8][4];
  #pragma unroll
  for (int i = 0; i < 8; ++i)
    #pragma unroll
    for (int j = 0; j < 4; ++j) acc[i][j] = {0.f, 0.f, 0.f, 0.f};

  auto issueA = [&](int k0t, f32x4* pv) {
    const f32x4* s = reinterpret_cast<const f32x4*>(aBase + k0t * 64);
    #pragma unroll
    for (int q = 0; q < 8; ++q) pv[q] = s[q];
  };
  auto issueB = [&](int k0t, char* bufB) {
    #pragma unroll
    for (int i = 0; i < 4; ++i) {
      const int ch = wid * 256 + i * 64;       // wave-uniform chunk base
      gload16(wsrc + ((size_t)k0t * 2048 + ch + lane) * 8, bufB + ch * 16);
    }
  };
  // write half the A regs (q = q0, q0+1) as two bf16x8 chunks
  auto writeA = [&](char* bufA, const f32x4* pv, int q0) {
    char* ab = bufA + arow * 128;
    #pragma unroll
    for (int q = q0; q < q0 + 2; ++q) {
      bf16x8 c;
      #pragma unroll
      for (int jj = 0; jj < 4; ++jj) {
        c[jj]     = cvt_bf16(pv[2 * q][jj]);
        c[4 + jj] = cvt_bf16(pv[2 * q + 1][jj]);
      }
      *reinterpret_cast<bf16x8*>(ab + (((ahalf * 4 + q) ^ (arow & 7)) << 4)) = c;
    }
  };
  // one cluster: all 32 MFMA for k-chunk group s
  auto cluster = [&](const char* bufA, const char* bufB, int s) {
    const int c16 = s * 4 + (lane >> 4);
    bf16x8 af[8];
    #pragma unroll
    for (int mt = 0; mt < 8; ++mt) {
      const int r = wm * 128 + mt * 16 + (lane & 15);
      af[mt] = *reinterpret_cast<const bf16x8*>(bufA + r * 128 + ((c16 ^ (r & 7)) << 4));
    }
    bf16x8 bf[4];
    #pragma unroll
    for (int nt = 0; nt < 4; ++nt) {
      const int cc = wn * 64 + nt * 16 + (lane & 15);
      bf[nt] = *reinterpret_cast<const bf16x8*>(bufB + cc * 128 + ((c16 ^ (cc & 7)) << 4));
    }
    __builtin_amdgcn_s_setprio(1);
    #pragma unroll
    for (int nt = 0; nt < 4; ++nt)
      #pragma unroll
      for (int mt = 0; mt < 8; ++mt)
        acc[mt][nt] = __builtin_amdgcn_mfma_f32_16x16x32_bf16(af[mt], bf[nt], acc[mt][nt], 0, 0, 0);
    __builtin_amdgcn_s_setprio(0);
  };

  // prologue: stage K-tile 0 into buffer 0
  {
    f32x4 pv[8];
    issueA(0, pv);
    issueB(0, smem + 32768);
    writeA(smem, pv, 0);
    writeA(smem, pv, 2);
    asm volatile("s_waitcnt vmcnt(0)" ::: "memory");
  }
  __syncthreads();

  int cur = 0;
  for (int t = 0; t < 64; ++t) {
    char* A  = smem + cur * 65536;
    char* B  = A + 32768;
    char* An = smem + (cur ^ 1) * 65536;
    char* Bn = An + 32768;
    f32x4 nv[8];
    if (t < 63) {                          // issue-early (T14): A->regs, B->LDS[next]
      issueA(t + 1, nv);
      issueB(t + 1, Bn);
      __builtin_amdgcn_sched_barrier(0);   // pin: all loads issued before MFMA
    }
    cluster(A, B, 0);                      // 32 MFMA
    if (t < 63) writeA(An, nv, 0);         // reg-dep wait on first 4 loads only
    cluster(A, B, 1);                      // 32 MFMA
    if (t < 63) {
      writeA(An, nv, 2);                   // reg-dep wait on last 4 loads
      asm volatile("s_waitcnt vmcnt(0)" ::: "memory");  // B tail only (A consumed)
    }
    __syncthreads();
    cur ^= 1;
  }

  // ---- epilogue: in-register softmax-pool; kv<->sc pairing via shfl_xor(8) ----
  const int win = rowblk * 2 + wm;       // global window id (= b*64 + nc)
  #pragma unroll
  for (int nt = 0; nt < 4; ++nt) {
    const int f  = wn * 4 + nt;
    const int ch = colblk * 128 + f * 8 + (lane & 7);
    if (lane & 8) {                      // hi lanes hold sc: add ape first
      #pragma unroll
      for (int mt = 0; mt < 8; ++mt)
        #pragma unroll
        for (int r = 0; r < 4; ++r) {
          const int rw = mt * 16 + ((lane >> 4) & 3) * 4 + r;
          acc[mt][nt][r] += ape[(size_t)rw * HEADDIM + ch];
        }
    }
    float m = -3.0e38f;
    #pragma unroll
    for (int mt = 0; mt < 8; ++mt)
      #pragma unroll
      for (int r = 0; r < 4; ++r) m = fmaxf(m, acc[mt][nt][r]);
    m = fmaxf(m, __shfl_xor(m, 16));
    m = fmaxf(m, __shfl_xor(m, 32));
    float den = 0.f, num = 0.f;
    #pragma unroll
    for (int mt = 0; mt < 8; ++mt)
      #pragma unroll
      for (int r = 0; r < 4; ++r) {
        const float other = __shfl_xor(acc[mt][nt][r], 8);  // hi lane gets kv
        const float e = __expf(acc[mt][nt][r] - m);
        den += e;
        num += e * other;
      }
    den += __shfl_xor(den, 16); den += __shfl_xor(den, 32);
    num += __shfl_xor(num, 16); num += __shfl_xor(num, 32);
    if ((lane & 8) && (lane < 16))
      comp[(size_t)win * HEADDIM + ch] = num / den;
  }
}

// ---------------- RMSNorm + RoPE + scatter (all f32) ----------------
__global__ __launch_bounds__(64) void finalize_kernel(
    const float* __restrict__ comp,
    const float* __restrict__ nw,
    const float* __restrict__ cosg,
    const float* __restrict__ sing,
    const int* __restrict__ bo,
    float* __restrict__ out) {
  const int win = blockIdx.x;          // 0..127
  const int b = win >> 6, nc = win & 63;
  const int t = threadIdx.x;
  const float* cw = comp + (size_t)win * HEADDIM;

  float v[8];
  float ss = 0.f;
  #pragma unroll
  for (int j = 0; j < 8; ++j) { v[j] = cw[t * 8 + j]; ss += v[j] * v[j]; }
  #pragma unroll
  for (int o = 32; o; o >>= 1) ss += __shfl_xor(ss, o);
  const float scale = rsqrtf(ss / 512.0f + 1e-6f);

  float w[8];
  #pragma unroll
  for (int j = 0; j < 8; ++j) w[j] = v[j] * scale * nw[t * 8 + j];

  const int phys = bo[b];
  float* op = out + ((size_t)phys * NCW + nc) * HEADDIM + t * 8;
  if (t * 8 < HEADDIM - RD) {
    #pragma unroll
    for (int j = 0; j < 8; ++j) op[j] = w[j];
  } else {
    const int pos = nc * RATIO;
    #pragma unroll
    for (int j = 0; j < 8; j += 2) {
      const int i = (t * 8 + j - (HEADDIM - RD)) >> 1;
      const float co = cosg[(size_t)pos * 32 + i];
      const float si = sing[(size_t)pos * 32 + i];
      op[j]     = w[j] * co - w[j + 1] * si;
      op[j + 1] = w[j] * si + w[j + 1] * co;
    }
  }
}

extern "C" void kernel_launch(void* const* d_in, const int* in_sizes, int n_in,
                              void* d_out, int out_size, void* d_ws, size_t ws_size,
                              hipStream_t stream) {
  const float* x     = (const float*)d_in[0];
  const float* wkv   = (const float*)d_in[1];
  const float* wgate = (const float*)d_in[2];
  const float* ape   = (const float*)d_in[3];
  const float* nw    = (const float*)d_in[4];
  const float* cosg  = (const float*)d_in[5];
  const float* sing  = (const float*)d_in[6];
  const int*   bo    = (const int*)d_in[7];
  float* out = (float*)d_out;

  __hip_bfloat16* wTs = (__hip_bfloat16*)d_ws;                        // 8 MB swizzled W'
  float* comp = (float*)((char*)d_ws + (size_t)8 * 1024 * 1024);      // 256 KB

  (void)hipMemsetAsync(d_out, 0, (size_t)out_size * sizeof(float), stream);
  prep_weights<<<dim3(64, 4), 256, 0, stream>>>(wkv, wgate, wTs);
  gemm_pool_kernel<<<dim3(256), 512, 0, stream>>>(x, wTs, ape, comp);
  finalize_kernel<<<dim3(128), 64, 0, stream>>>(comp, nw, cosg, sing, bo, out);
}